// Round 7
// baseline (1729.000 us; speedup 1.0000x reference)
//
#include <hip/hip_runtime.h>
#include <math.h>

#define V 128000
#define H 1024
#define NBLK 2048              // 8 blocks/CU x 256 CUs, all co-resident
#define NCHUNK 8000            // V / 16 rows per chunk
#define R_CACHED 48000

typedef float f32x4 __attribute__((ext_vector_type(4)));

// ws uint32 layout:
//   barrier A counters: u32[0 + i*16], i<8 (64B apart)   flag: u32[128]
//   barrier B counters: u32[192 + i*16]                  flag: u32[320]
// ws float layout:
//   gi: f32[512 .. 512+3072)   gh: f32[3584 .. 3584+3072)
//   per-wave partials (m,s): f32[6656 + 2*w), w < 8192
#define BARA_CNT 0
#define BARA_FLG 128
#define BARB_CNT 192
#define BARB_FLG 320
#define ZERO_N   384
#define GI_F     512
#define GH_F     (512 + 3072)
#define PART_F   6656
#define NWAVE    (NBLK * 4)    // 8192

__global__ __launch_bounds__(384) void k_init(unsigned* __restrict__ wsu) {
    if (threadIdx.x < ZERO_N) wsu[threadIdx.x] = 0u;
}

__device__ __forceinline__ float wave_reduce_sum(float v) {
#pragma unroll
    for (int off = 32; off > 0; off >>= 1)
        v += __shfl_xor(v, off, 64);
    return v;
}

// Device-wide barrier: 8 spread arrival counters -> master sets flag.
// All NBLK blocks are co-resident by __launch_bounds__(256,8) construction.
__device__ __forceinline__ void grid_barrier(unsigned* cnt, unsigned* flg) {
    __syncthreads();
    if (threadIdx.x == 0) {
        __threadfence();
        __hip_atomic_fetch_add(cnt + (blockIdx.x & 7) * 16, 1u,
                               __ATOMIC_RELEASE, __HIP_MEMORY_SCOPE_AGENT);
        if (blockIdx.x == 0) {
            unsigned s;
            do {
                s = 0;
#pragma unroll
                for (int i = 0; i < 8; ++i)
                    s += __hip_atomic_load(cnt + i * 16, __ATOMIC_ACQUIRE,
                                           __HIP_MEMORY_SCOPE_AGENT);
                if (s < NBLK) __builtin_amdgcn_s_sleep(8);
            } while (s < NBLK);
            __hip_atomic_store(flg, 1u, __ATOMIC_RELEASE, __HIP_MEMORY_SCOPE_AGENT);
        } else {
            while (!__hip_atomic_load(flg, __ATOMIC_ACQUIRE, __HIP_MEMORY_SCOPE_AGENT))
                __builtin_amdgcn_s_sleep(16);
        }
        __threadfence();
    }
    __syncthreads();
}

__global__ __launch_bounds__(256, 8) void k_all(
    const int* __restrict__ token_p, const float* __restrict__ hidden,
    const float* __restrict__ emb,
    const float* __restrict__ w_ih, const float* __restrict__ w_hh,
    const float* __restrict__ b_ih, const float* __restrict__ b_hh,
    const float* __restrict__ w_out, const float* __restrict__ b_out,
    float* __restrict__ d_out, float* __restrict__ ws_f)
{
    unsigned* wsu = (unsigned*)ws_f;
    __shared__ float hsh[H];
    __shared__ float sm[256], ss[256];
    __shared__ float sC;

    const int wave = threadIdx.x >> 6;
    const int lane = threadIdx.x & 63;

    // ---------------- Phase 1: gate dots. One wave per row of w_ih / w_hh.
    {
        const int gw = blockIdx.x * 4 + wave;   // 0 .. 8191; 6144 active
        if (gw < 6144) {
            const float* w; const float* vec; float bias; float* out;
            if (gw < 3072) {
                w    = w_ih + (size_t)gw * H;
                vec  = emb + (size_t)token_p[0] * H;  // low 32b ok (i32/i64 LE)
                bias = b_ih[gw];
                out  = ws_f + GI_F + gw;
            } else {
                const int r2 = gw - 3072;
                w    = w_hh + (size_t)r2 * H;
                vec  = hidden;
                bias = b_hh[r2];
                out  = ws_f + GH_F + r2;
            }
            const f32x4* w4 = (const f32x4*)w;
            const f32x4* v4 = (const f32x4*)vec;
            float acc = 0.f;
#pragma unroll
            for (int it = 0; it < 4; ++it) {
                f32x4 a = w4[it * 64 + lane];
                f32x4 b = v4[it * 64 + lane];
                acc = fmaf(a.x, b.x, acc);
                acc = fmaf(a.y, b.y, acc);
                acc = fmaf(a.z, b.z, acc);
                acc = fmaf(a.w, b.w, acc);
            }
            acc = wave_reduce_sum(acc);
            if (lane == 0) *out = acc + bias;
        }
    }

    grid_barrier(wsu + BARA_CNT, wsu + BARA_FLG);

    // ---------------- Phase 2 prologue: every block builds h_new in LDS.
    {
        const int t = threadIdx.x;
#pragma unroll
        for (int q = 0; q < 4; ++q) {
            const int k = q * 256 + t;
            const float gr = ws_f[GI_F + k]         + ws_f[GH_F + k];
            const float gz = ws_f[GI_F + H + k]     + ws_f[GH_F + H + k];
            const float r = 1.f / (1.f + expf(-gr));
            const float z = 1.f / (1.f + expf(-gz));
            const float n = tanhf(ws_f[GI_F + 2 * H + k] + r * ws_f[GH_F + 2 * H + k]);
            const float hn = (1.f - z) * n + z * hidden[k];
            hsh[k] = hn;
            if (blockIdx.x == 0) d_out[V + k] = hn;   // h_new output
        }
    }
    __syncthreads();

    // ---------------- Phase 2: logits stream; per-wave register online softmax.
    {
        const f32x4* hp = (const f32x4*)hsh;
        f32x4 h4[4];
#pragma unroll
        for (int it = 0; it < 4; ++it) h4[it] = hp[it * 64 + lane];

        float pm = -INFINITY, ps = 0.f;

        for (int c = blockIdx.x; c < NCHUNK; c += NBLK) {
            const int base_row = c * 16 + wave * 4;
            float acc[4] = {0.f, 0.f, 0.f, 0.f};

            if (base_row + 3 < R_CACHED) {
#pragma unroll
                for (int i = 0; i < 4; ++i) {
                    const f32x4* w4 = (const f32x4*)(w_out + (size_t)(base_row + i) * H);
#pragma unroll
                    for (int it = 0; it < 4; ++it) {
                        f32x4 a = w4[it * 64 + lane];
                        acc[i] = fmaf(a.x, h4[it].x, acc[i]);
                        acc[i] = fmaf(a.y, h4[it].y, acc[i]);
                        acc[i] = fmaf(a.z, h4[it].z, acc[i]);
                        acc[i] = fmaf(a.w, h4[it].w, acc[i]);
                    }
                }
            } else {
#pragma unroll
                for (int i = 0; i < 4; ++i) {
                    const f32x4* w4 = (const f32x4*)(w_out + (size_t)(base_row + i) * H);
#pragma unroll
                    for (int it = 0; it < 4; ++it) {
                        f32x4 a = __builtin_nontemporal_load(w4 + it * 64 + lane);
                        acc[i] = fmaf(a.x, h4[it].x, acc[i]);
                        acc[i] = fmaf(a.y, h4[it].y, acc[i]);
                        acc[i] = fmaf(a.z, h4[it].z, acc[i]);
                        acc[i] = fmaf(a.w, h4[it].w, acc[i]);
                    }
                }
            }

#pragma unroll
            for (int i = 0; i < 4; ++i) {
                const float r = wave_reduce_sum(acc[i]);
                const float l = r + b_out[base_row + i];
                if (lane == 0) d_out[base_row + i] = l;
                // all lanes redundantly track (m, s) — no LDS, no sync
                if (l > pm) { ps = ps * expf(pm - l) + 1.f; pm = l; }
                else        { ps += expf(l - pm); }
            }
        }

        const int wid = blockIdx.x * 4 + wave;
        if (lane == 0) {
            ws_f[PART_F + 2 * wid]     = pm;
            ws_f[PART_F + 2 * wid + 1] = ps;
        }
    }

    grid_barrier(wsu + BARB_CNT, wsu + BARB_FLG);

    // ---------------- Phase 3: blocks 0..124 merge partials -> C; subtract.
    if (blockIdx.x < 125) {
        const int t = threadIdx.x;
        float m = -INFINITY, s = 0.f;
        for (int j = t; j < NWAVE; j += 256) {
            const float m2 = ws_f[PART_F + 2 * j];
            const float s2 = ws_f[PART_F + 2 * j + 1];
            if (m2 > m) { s = s * expf(m - m2) + s2; m = m2; }
            else        { s += s2 * expf(m2 - m); }
        }
        sm[t] = m; ss[t] = s;
        __syncthreads();
#pragma unroll
        for (int off = 128; off > 0; off >>= 1) {
            if (t < off) {
                const float m2 = sm[t + off], s2 = ss[t + off];
                float mm = sm[t], sc = ss[t];
                if (m2 > mm) { sc = sc * expf(mm - m2) + s2; mm = m2; }
                else         { sc += s2 * expf(m2 - mm); }
                sm[t] = mm; ss[t] = sc;
            }
            __syncthreads();
        }
        if (t == 0) sC = sm[0] + logf(ss[0]);
        __syncthreads();
        const float C = sC;

        const int idx = blockIdx.x * 256 + t;     // < 32000 exactly covers V/4
        f32x4* o4 = (f32x4*)d_out;
        f32x4 v = o4[idx];
        v.x -= C; v.y -= C; v.z -= C; v.w -= C;
        o4[idx] = v;
    }
}

extern "C" void kernel_launch(void* const* d_in, const int* in_sizes, int n_in,
                              void* d_out_v, int out_size, void* d_ws, size_t ws_size,
                              hipStream_t stream) {
    const int*   token  = (const int*)d_in[0];
    const float* hidden = (const float*)d_in[1];
    const float* emb    = (const float*)d_in[2];
    const float* w_ih   = (const float*)d_in[3];
    const float* w_hh   = (const float*)d_in[4];
    const float* b_ih   = (const float*)d_in[5];
    const float* b_hh   = (const float*)d_in[6];
    const float* w_out  = (const float*)d_in[7];
    const float* b_out  = (const float*)d_in[8];
    float* d_out = (float*)d_out_v;
    float* ws    = (float*)d_ws;

    k_init<<<1, 384, 0, stream>>>((unsigned*)ws);
    k_all <<<NBLK, 256, 0, stream>>>(token, hidden, emb, w_ih, w_hh, b_ih, b_hh,
                                     w_out, b_out, d_out, ws);
}

// Round 8
// 98.231 us; speedup vs baseline: 17.6014x; 17.6014x over previous
//
#include <hip/hip_runtime.h>
#include <math.h>

#define V 128000
#define H 1024
#define H3 3072

typedef float f32x4 __attribute__((ext_vector_type(4)));

// ws layout (float offsets)
#define GI_OFF 0                 // 3072
#define GH_OFF 3072              // 3072
#define ROWS_PER_BLK 16
#define NBLK3 (V / ROWS_PER_BLK) // 8000 blocks for logits kernel
#define PART_OFF 6144            // 2 * NBLK3 = 16000
#define RED_OFF (PART_OFF + 2 * NBLK3)  // 22144

// Rows [0, R_CACHED) of w_out use normal (cacheable) loads -> Infinity-Cache
// resident across clean graph replays (196.6 MB + 25 MB gates < 256 MiB L3).
// Rows >= R_CACHED use non-temporal loads -> stream from HBM without
// evicting the resident head. (R6's FETCH counter proved L3 retention
// across replays is real; R2 measured 98.9 us with this exact split.)
#define R_CACHED 48000

__device__ __forceinline__ float wave_reduce_sum(float v) {
#pragma unroll
    for (int off = 32; off > 0; off >>= 1)
        v += __shfl_xor(v, off, 64);
    return v;
}

// Kernel 1: gi[j] = dot(w_ih[j], x) + b_ih[j];  gh[j] = dot(w_hh[j], h) + b_hh[j]
__global__ __launch_bounds__(256) void k_gates(
    const int* __restrict__ token_p, const float* __restrict__ hidden,
    const float* __restrict__ emb,
    const float* __restrict__ w_ih, const float* __restrict__ w_hh,
    const float* __restrict__ b_ih, const float* __restrict__ b_hh,
    float* __restrict__ ws)
{
    const int gwave = (int)((blockIdx.x * blockDim.x + threadIdx.x) >> 6);
    const int lane  = threadIdx.x & 63;
    if (gwave >= 2 * H3) return;

    const float* w;
    const float* vec;
    float bias;
    float* out;
    if (gwave < H3) {
        const int row = gwave;
        w    = w_ih + (size_t)row * H;
        vec  = emb + (size_t)token_p[0] * H;   // low 32 bits fine for i32/i64 LE
        bias = b_ih[row];
        out  = ws + GI_OFF + row;
    } else {
        const int row = gwave - H3;
        w    = w_hh + (size_t)row * H;
        vec  = hidden;
        bias = b_hh[row];
        out  = ws + GH_OFF + row;
    }

    const f32x4* w4 = (const f32x4*)w;
    const f32x4* v4 = (const f32x4*)vec;
    float acc = 0.f;
#pragma unroll
    for (int it = 0; it < 4; ++it) {
        f32x4 a = w4[it * 64 + lane];
        f32x4 b = v4[it * 64 + lane];
        acc = fmaf(a.x, b.x, acc);
        acc = fmaf(a.y, b.y, acc);
        acc = fmaf(a.z, b.z, acc);
        acc = fmaf(a.w, b.w, acc);
    }
    acc = wave_reduce_sum(acc);
    if (lane == 0) *out = acc + bias;
}

// Kernel 2: gates -> h_new, written to d_out[V .. V+H)
__global__ __launch_bounds__(256) void k_combine(
    const float* __restrict__ hidden, const float* __restrict__ ws,
    float* __restrict__ d_out)
{
    const int k = blockIdx.x * blockDim.x + threadIdx.x;
    if (k >= H) return;
    const float gr  = ws[GI_OFF + k]         + ws[GH_OFF + k];
    const float gz  = ws[GI_OFF + H + k]     + ws[GH_OFF + H + k];
    const float gin = ws[GI_OFF + 2 * H + k];
    const float ghn = ws[GH_OFF + 2 * H + k];
    const float r = 1.f / (1.f + expf(-gr));
    const float z = 1.f / (1.f + expf(-gz));
    const float n = tanhf(gin + r * ghn);
    d_out[V + k] = (1.f - z) * n + z * hidden[k];
}

// Kernel 3: logits[row] = dot(w_out[row], h_new) + b_out[row]
// 4 waves/block, 4 rows/wave, 4 independent accumulators;
// cached contiguous head, non-temporal tail. Emits per-block (max, sumexp).
__global__ __launch_bounds__(256) void k_logits(
    const float* __restrict__ w_out, const float* __restrict__ b_out,
    float* __restrict__ d_out, float* __restrict__ ws)
{
    __shared__ float sl[ROWS_PER_BLK];
    const int wave = threadIdx.x >> 6;
    const int lane = threadIdx.x & 63;

    // preload h_new (4 KB, cache-hot) into registers, reused across rows
    const f32x4* h4p = (const f32x4*)(d_out + V);
    f32x4 h4[4];
#pragma unroll
    for (int it = 0; it < 4; ++it) h4[it] = h4p[it * 64 + lane];

    const int base_row = blockIdx.x * ROWS_PER_BLK + wave * 4;
    float acc[4] = {0.f, 0.f, 0.f, 0.f};

    if (base_row + 3 < R_CACHED) {
#pragma unroll
        for (int i = 0; i < 4; ++i) {
            const f32x4* w4 = (const f32x4*)(w_out + (size_t)(base_row + i) * H);
#pragma unroll
            for (int it = 0; it < 4; ++it) {
                f32x4 a = w4[it * 64 + lane];
                acc[i] = fmaf(a.x, h4[it].x, acc[i]);
                acc[i] = fmaf(a.y, h4[it].y, acc[i]);
                acc[i] = fmaf(a.z, h4[it].z, acc[i]);
                acc[i] = fmaf(a.w, h4[it].w, acc[i]);
            }
        }
    } else {
#pragma unroll
        for (int i = 0; i < 4; ++i) {
            const f32x4* w4 = (const f32x4*)(w_out + (size_t)(base_row + i) * H);
#pragma unroll
            for (int it = 0; it < 4; ++it) {
                f32x4 a = __builtin_nontemporal_load(w4 + it * 64 + lane);
                acc[i] = fmaf(a.x, h4[it].x, acc[i]);
                acc[i] = fmaf(a.y, h4[it].y, acc[i]);
                acc[i] = fmaf(a.z, h4[it].z, acc[i]);
                acc[i] = fmaf(a.w, h4[it].w, acc[i]);
            }
        }
    }

#pragma unroll
    for (int i = 0; i < 4; ++i) {
        const float r = wave_reduce_sum(acc[i]);
        if (lane == 0) {
            const float l = r + b_out[base_row + i];
            d_out[base_row + i] = l;
            sl[wave * 4 + i] = l;
        }
    }
    __syncthreads();
    if (threadIdx.x == 0) {
        float m = sl[0];
#pragma unroll
        for (int i = 1; i < ROWS_PER_BLK; ++i) m = fmaxf(m, sl[i]);
        float s = 0.f;
#pragma unroll
        for (int i = 0; i < ROWS_PER_BLK; ++i) s += expf(sl[i] - m);
        ws[PART_OFF + 2 * blockIdx.x]     = m;
        ws[PART_OFF + 2 * blockIdx.x + 1] = s;
    }
}

// Kernel 4: merge 8000 (max,sumexp) partials -> C = M + log(S)
__global__ __launch_bounds__(1024) void k_reduce(float* __restrict__ ws)
{
    __shared__ float sm[1024], ss[1024];
    const int t = threadIdx.x;
    float m = -INFINITY, s = 0.f;
    for (int i = t; i < NBLK3; i += 1024) {
        const float m2 = ws[PART_OFF + 2 * i];
        const float s2 = ws[PART_OFF + 2 * i + 1];
        if (m2 > m) { s = s * expf(m - m2) + s2; m = m2; }
        else        { s += s2 * expf(m2 - m); }
    }
    sm[t] = m; ss[t] = s;
    __syncthreads();
    for (int off = 512; off > 0; off >>= 1) {
        if (t < off) {
            float m2 = sm[t + off], s2 = ss[t + off];
            float mm = sm[t],       sc = ss[t];
            if (m2 > mm) { sc = sc * expf(mm - m2) + s2; mm = m2; }
            else         { sc += s2 * expf(m2 - mm); }
            sm[t] = mm; ss[t] = sc;
        }
        __syncthreads();
    }
    if (t == 0) ws[RED_OFF] = sm[0] + logf(ss[0]);
}

// Kernel 5: log_probs[i] = logits[i] - C, in place
__global__ __launch_bounds__(256) void k_final(
    float* __restrict__ d_out, const float* __restrict__ ws)
{
    const int i = blockIdx.x * blockDim.x + threadIdx.x;
    if (i < V) d_out[i] -= ws[RED_OFF];
}

extern "C" void kernel_launch(void* const* d_in, const int* in_sizes, int n_in,
                              void* d_out_v, int out_size, void* d_ws, size_t ws_size,
                              hipStream_t stream) {
    const int*   token  = (const int*)d_in[0];
    const float* hidden = (const float*)d_in[1];
    const float* emb    = (const float*)d_in[2];
    const float* w_ih   = (const float*)d_in[3];
    const float* w_hh   = (const float*)d_in[4];
    const float* b_ih   = (const float*)d_in[5];
    const float* b_hh   = (const float*)d_in[6];
    const float* w_out  = (const float*)d_in[7];
    const float* b_out  = (const float*)d_in[8];
    float* d_out = (float*)d_out_v;
    float* ws    = (float*)d_ws;

    k_gates  <<<(2 * H3) / 4, 256, 0, stream>>>(token, hidden, emb, w_ih, w_hh, b_ih, b_hh, ws);
    k_combine<<<(H + 255) / 256, 256, 0, stream>>>(hidden, ws, d_out);
    k_logits <<<NBLK3, 256, 0, stream>>>(w_out, b_out, d_out, ws);
    k_reduce <<<1, 1024, 0, stream>>>(ws);
    k_final  <<<(V + 255) / 256, 256, 0, stream>>>(d_out, ws);
}